// Round 2
// baseline (47311.868 us; speedup 1.0000x reference)
//
#include <hip/hip_runtime.h>
#include <hip/hip_fp16.h>

namespace {

constexpr int kS  = 1024;   // SEQ
constexpr int kI  = 64;     // INPUT_SIZE
constexpr int kH  = 128;    // HIDDEN
constexpr int kG  = 512;    // 4*HIDDEN
constexpr int kTB = 64;     // x staging block (steps)

typedef _Float16 h2v __attribute__((ext_vector_type(2)));

__device__ __forceinline__ float dot2(unsigned a, __half2 b, float c) {
#if __has_builtin(__builtin_amdgcn_fdot2)
  return __builtin_amdgcn_fdot2(__builtin_bit_cast(h2v, a),
                                __builtin_bit_cast(h2v, b), c, false);
#else
  __half2 ah = __builtin_bit_cast(__half2, a);
  c = fmaf(__half2float(__low2half(ah)),  __half2float(__low2half(b)),  c);
  c = fmaf(__half2float(__high2half(ah)), __half2float(__high2half(b)), c);
  return c;
#endif
}

__device__ __forceinline__ unsigned packh2(float lo, float hi) {
  __half2 h = __floats2half2_rn(lo, hi);
  return __builtin_bit_cast(unsigned, h);
}

// Opaque pin: forbids rematerialization of the weight value, forcing true
// VGPR residency across the whole t-loop (rule-17 trick).
__device__ __forceinline__ void pin(unsigned& v) { asm volatile("" : "+v"(v)); }

__device__ __forceinline__ float rcpf(float x) {
#if __has_builtin(__builtin_amdgcn_rcpf)
  return __builtin_amdgcn_rcpf(x);
#else
  return 1.0f / x;
#endif
}
__device__ __forceinline__ float sigf(float x)  { return rcpf(1.0f + __expf(-x)); }
__device__ __forceinline__ float tanhff(float x){ return 1.0f - 2.0f * rcpf(1.0f + __expf(2.0f * x)); }

// Fused 2-layer LSTM + head. 512 blocks x 512 threads; block b owns chain b.
// Thread tid owns gate row tid of BOTH layers (weights pinned in VGPRs).
// Super-step t: gates1(t) [from x(t), h1(t-1)] and gates2(t-1) [from h1(t-1),
// h2(t-2)] computed together; one gbuf exchange + activation per step.
__global__ __launch_bounds__(512, 4) void lstm_fused(
    const float* __restrict__ x,
    const float* __restrict__ Wx1, const float* __restrict__ bx1,
    const float* __restrict__ Wh1, const float* __restrict__ bh1,
    const float* __restrict__ Wx2, const float* __restrict__ bx2,
    const float* __restrict__ Wh2, const float* __restrict__ bh2,
    const float* __restrict__ Wc,  const float* __restrict__ bc,
    float* __restrict__ out)
{
  const int tid = threadIdx.x;
  const int b   = blockIdx.x;

  __shared__ __align__(16) __half2 xs[kTB][kI/2];    // 8 KiB staged x (fp16)
  __shared__ __align__(16) __half2 h1buf[2][kH/2];   // 512 B double-buffered h1
  __shared__ __align__(16) __half2 h2buf[2][kH/2];   // 512 B double-buffered h2
  __shared__ float g1[kG];                           // 2 KiB gate preacts L1
  __shared__ float g2[kG];                           // 2 KiB gate preacts L2
  __shared__ float hfin[kH];                         // final h2 (fp32)

  // ---- load weight rows for gate row tid into VGPRs (packed fp16) ----
  unsigned wx1[kI/2], wh1[kH/2], wx2[kH/2], wh2[kH/2];
  {
    const float4* p = reinterpret_cast<const float4*>(Wx1 + (size_t)tid * kI);
#pragma unroll
    for (int i = 0; i < kI/4; ++i) {
      float4 v = p[i]; wx1[2*i] = packh2(v.x, v.y); wx1[2*i+1] = packh2(v.z, v.w);
    }
  }
  {
    const float4* p = reinterpret_cast<const float4*>(Wh1 + (size_t)tid * kH);
    const float4* q = reinterpret_cast<const float4*>(Wx2 + (size_t)tid * kH);
    const float4* r = reinterpret_cast<const float4*>(Wh2 + (size_t)tid * kH);
#pragma unroll
    for (int i = 0; i < kH/4; ++i) {
      float4 v = p[i]; wh1[2*i] = packh2(v.x, v.y); wh1[2*i+1] = packh2(v.z, v.w);
      float4 w = q[i]; wx2[2*i] = packh2(w.x, w.y); wx2[2*i+1] = packh2(w.z, w.w);
      float4 u = r[i]; wh2[2*i] = packh2(u.x, u.y); wh2[2*i+1] = packh2(u.z, u.w);
    }
  }
#pragma unroll
  for (int i = 0; i < kI/2; ++i) pin(wx1[i]);
#pragma unroll
  for (int i = 0; i < kH/2; ++i) { pin(wh1[i]); pin(wx2[i]); pin(wh2[i]); }

  const float bias1 = bx1[tid] + bh1[tid];
  const float bias2 = bx2[tid] + bh2[tid];

  // zero-init both h double buffers (256 __half2 total)
  {
    const __half2 z = __float2half2_rn(0.0f);
    if (tid < 128)      (&h1buf[0][0])[tid]       = z;
    else if (tid < 256) (&h2buf[0][0])[tid - 128] = z;
  }
  float cst = 0.0f;   // c1 for tid<128, c2 for 128<=tid<256

  for (int t0 = 0; t0 < kS; t0 += kTB) {
    // stage x[b][t0..t0+63][:] -> fp16 LDS (1024 float4 over 512 threads)
#pragma unroll
    for (int q = 0; q < 2; ++q) {
      const int idx = q * 512 + tid;
      const int dt = idx >> 4, i4 = idx & 15;
      const float4 v = *reinterpret_cast<const float4*>(
          x + ((size_t)b * kS + (size_t)(t0 + dt)) * kI + i4 * 4);
      xs[dt][i4*2]   = __floats2half2_rn(v.x, v.y);
      xs[dt][i4*2+1] = __floats2half2_rn(v.z, v.w);
    }
    __syncthreads();   // publishes xs (and h/c init on first iteration)

    for (int dt = 0; dt < kTB; ++dt) {
      const int t = t0 + dt;
      const __half2* __restrict__ h1p = h1buf[(t + 1) & 1];  // h1(t-1)
      const __half2* __restrict__ h2p = h2buf[t & 1];        // h2(t-2)

      float a1 = bias1, a1b = 0.0f, a2 = bias2, a2b = 0.0f;
#pragma unroll
      for (int p = 0; p < kI/2; p += 2) {
        a1  = dot2(wx1[p],   xs[dt][p],   a1);
        a1b = dot2(wx1[p+1], xs[dt][p+1], a1b);
      }
#pragma unroll
      for (int p = 0; p < kH/2; p += 2) {
        const __half2 hA = h1p[p], hB = h1p[p+1];   // shared by both layers
        a1  = dot2(wh1[p],   hA, a1);
        a2  = dot2(wx2[p],   hA, a2);
        a1b = dot2(wh1[p+1], hB, a1b);
        a2b = dot2(wx2[p+1], hB, a2b);
      }
#pragma unroll
      for (int p = 0; p < kH/2; p += 2) {
        a2  = dot2(wh2[p],   h2p[p],   a2);
        a2b = dot2(wh2[p+1], h2p[p+1], a2b);
      }
      g1[tid] = a1 + a1b;
      g2[tid] = a2 + a2b;
      __syncthreads();

      if (tid < 128) {                  // layer-1 cell j = tid -> h1(t)
        const int j = tid;
        const float gi = g1[j], gf = g1[j+128], gg = g1[j+256], go = g1[j+384];
        cst = sigf(gf) * cst + sigf(gi) * tanhff(gg);
        reinterpret_cast<__half*>(h1buf[t & 1])[j] =
            __float2half_rn(sigf(go) * tanhff(cst));
      } else if (tid < 256 && t > 0) {  // layer-2 cell -> h2(t-1)
        const int j = tid - 128;
        const float gi = g2[j], gf = g2[j+128], gg = g2[j+256], go = g2[j+384];
        cst = sigf(gf) * cst + sigf(gi) * tanhff(gg);
        reinterpret_cast<__half*>(h2buf[(t + 1) & 1])[j] =
            __float2half_rn(sigf(go) * tanhff(cst));
      }
      __syncthreads();
    }
  }

  // epilogue super-step t=1024: gates2(1023) from h1(1023)=h1buf[1], h2(1022)=h2buf[0]
  {
    const __half2* __restrict__ h1p = h1buf[1];
    const __half2* __restrict__ h2p = h2buf[0];
    float a2 = bias2, a2b = 0.0f;
#pragma unroll
    for (int p = 0; p < kH/2; p += 2) {
      a2  = dot2(wx2[p],   h1p[p],   a2);
      a2b = dot2(wx2[p+1], h1p[p+1], a2b);
      a2  = dot2(wh2[p],   h2p[p],   a2);
      a2b = dot2(wh2[p+1], h2p[p+1], a2b);
    }
    g2[tid] = a2 + a2b;
    __syncthreads();
    if (tid >= 128 && tid < 256) {
      const int j = tid - 128;
      const float gi = g2[j], gf = g2[j+128], gg = g2[j+256], go = g2[j+384];
      cst = sigf(gf) * cst + sigf(gi) * tanhff(gg);
      hfin[j] = sigf(go) * tanhff(cst);
    }
    __syncthreads();
  }

  // classifier head: logits[b, n] = Wc[n,:] . h2fin + bc[n]
  if (tid < 4) {
    const float* wr = Wc + (size_t)tid * kH;
    float s0 = 0.f, s1 = 0.f, s2 = 0.f, s3 = 0.f;
#pragma unroll
    for (int j = 0; j < kH; j += 4) {
      s0 = fmaf(wr[j],   hfin[j],   s0);
      s1 = fmaf(wr[j+1], hfin[j+1], s1);
      s2 = fmaf(wr[j+2], hfin[j+2], s2);
      s3 = fmaf(wr[j+3], hfin[j+3], s3);
    }
    out[(size_t)b * 4 + tid] = bc[tid] + ((s0 + s1) + (s2 + s3));
  }
}

} // namespace

extern "C" void kernel_launch(void* const* d_in, const int* in_sizes, int n_in,
                              void* d_out, int out_size, void* d_ws, size_t ws_size,
                              hipStream_t stream) {
  const float* x   = (const float*)d_in[0];
  const float* Wx1 = (const float*)d_in[1];
  const float* bx1 = (const float*)d_in[2];
  const float* Wh1 = (const float*)d_in[3];
  const float* bh1 = (const float*)d_in[4];
  const float* Wx2 = (const float*)d_in[5];
  const float* bx2 = (const float*)d_in[6];
  const float* Wh2 = (const float*)d_in[7];
  const float* bh2 = (const float*)d_in[8];
  const float* Wc  = (const float*)d_in[9];
  const float* bc  = (const float*)d_in[10];

  hipLaunchKernelGGL(lstm_fused, dim3(512), dim3(512), 0, stream,
                     x, Wx1, bx1, Wh1, bh1, Wx2, bx2, Wh2, bh2, Wc, bc,
                     (float*)d_out);
}

// Round 3
// 4710.389 us; speedup vs baseline: 10.0442x; 10.0442x over previous
//
#include <hip/hip_runtime.h>
#include <hip/hip_fp16.h>

namespace {

constexpr int kS  = 1024;   // SEQ
constexpr int kI  = 64;     // INPUT_SIZE
constexpr int kH  = 128;    // HIDDEN
constexpr int kG  = 512;    // 4*HIDDEN
constexpr int kTB = 64;     // x staging block (steps)

typedef _Float16 h2v __attribute__((ext_vector_type(2)));

__device__ __forceinline__ float dot2u(unsigned a, unsigned b, float c) {
#if __has_builtin(__builtin_amdgcn_fdot2)
  return __builtin_amdgcn_fdot2(__builtin_bit_cast(h2v, a),
                                __builtin_bit_cast(h2v, b), c, false);
#else
  __half2 ah = __builtin_bit_cast(__half2, a);
  __half2 bh = __builtin_bit_cast(__half2, b);
  c = fmaf(__half2float(__low2half(ah)),  __half2float(__low2half(bh)),  c);
  c = fmaf(__half2float(__high2half(ah)), __half2float(__high2half(bh)), c);
  return c;
#endif
}

__device__ __forceinline__ unsigned packh2(float lo, float hi) {
  __half2 h = __floats2half2_rn(lo, hi);
  return __builtin_bit_cast(unsigned, h);
}

__device__ __forceinline__ float rcpf(float x) {
#if __has_builtin(__builtin_amdgcn_rcpf)
  return __builtin_amdgcn_rcpf(x);
#else
  return 1.0f / x;
#endif
}
__device__ __forceinline__ float sigf(float x)  { return rcpf(1.0f + __expf(-x)); }
__device__ __forceinline__ float tanhff(float x){ return 1.0f - 2.0f * rcpf(1.0f + __expf(2.0f * x)); }

// Fused 2-layer LSTM + head. 256 blocks x 512 threads; block handles chains
// b0, b0+1. Thread tid owns gate row tid of BOTH layers for both chains;
// weights live in VGPRs (cap 256 via launch_bounds(512,2) -> 2 waves/SIMD).
// Super-step t computes gates1(t) and gates2(t-1) (both read h1(t-1)).
__global__ __launch_bounds__(512, 2) void lstm_fused(
    const float* __restrict__ x,
    const float* __restrict__ Wx1, const float* __restrict__ bx1,
    const float* __restrict__ Wh1, const float* __restrict__ bh1,
    const float* __restrict__ Wx2, const float* __restrict__ bx2,
    const float* __restrict__ Wh2, const float* __restrict__ bh2,
    const float* __restrict__ Wc,  const float* __restrict__ bc,
    float* __restrict__ out)
{
  const int tid = threadIdx.x;
  const int b0  = blockIdx.x * 2;

  __shared__ __align__(16) unsigned xs[kTB][2][kI/2];    // 16 KiB staged x (fp16)
  __shared__ __align__(16) unsigned h1buf[2][2][kH/2];   // [buf][chain][pair] 1 KiB
  __shared__ __align__(16) unsigned h2buf[2][2][kH/2];   // 1 KiB
  __shared__ float g1[2][kG];                            // 4 KiB gate preacts L1
  __shared__ float g2[2][kG];                            // 4 KiB gate preacts L2
  __shared__ float hfin[2][kH];                          // final h2 (fp32)

  // ---- load weight rows for gate row tid (packed fp16, kept in VGPRs) ----
  unsigned wx1[kI/2], wh1[kH/2], wx2[kH/2], wh2[kH/2];
  {
    const float4* p = reinterpret_cast<const float4*>(Wx1 + (size_t)tid * kI);
#pragma unroll
    for (int i = 0; i < kI/4; ++i) {
      float4 v = p[i]; wx1[2*i] = packh2(v.x, v.y); wx1[2*i+1] = packh2(v.z, v.w);
    }
    const float4* q = reinterpret_cast<const float4*>(Wh1 + (size_t)tid * kH);
    const float4* r = reinterpret_cast<const float4*>(Wx2 + (size_t)tid * kH);
    const float4* s = reinterpret_cast<const float4*>(Wh2 + (size_t)tid * kH);
#pragma unroll
    for (int i = 0; i < kH/4; ++i) {
      float4 v = q[i]; wh1[2*i] = packh2(v.x, v.y); wh1[2*i+1] = packh2(v.z, v.w);
      float4 w = r[i]; wx2[2*i] = packh2(w.x, w.y); wx2[2*i+1] = packh2(w.z, w.w);
      float4 u = s[i]; wh2[2*i] = packh2(u.x, u.y); wh2[2*i+1] = packh2(u.z, u.w);
    }
  }
  const float bias1 = bx1[tid] + bh1[tid];
  const float bias2 = bx2[tid] + bh2[tid];

  // zero-init both h double buffers (256 + 256 unsigned)
  if (tid < 256) reinterpret_cast<unsigned*>(h1buf)[tid]       = 0u;
  else           reinterpret_cast<unsigned*>(h2buf)[tid - 256] = 0u;
  float cst = 0.0f;   // c1 for tid<256 (chain tid>>7), c2 for tid>=256

  for (int t0 = 0; t0 < kS; t0 += kTB) {
    // stage x[b0..b0+1][t0..t0+63][:] -> fp16 LDS (2048 float4 over 512 thr)
#pragma unroll
    for (int q = 0; q < 4; ++q) {
      const int idx = q * 512 + tid;
      const int c   = idx >> 10;
      const int rem = idx & 1023;
      const int dt  = rem >> 4;
      const int i4  = rem & 15;
      const float4 v = *reinterpret_cast<const float4*>(
          x + ((size_t)(b0 + c) * kS + (size_t)(t0 + dt)) * kI + i4 * 4);
      xs[dt][c][i4*2]   = packh2(v.x, v.y);
      xs[dt][c][i4*2+1] = packh2(v.z, v.w);
    }
    __syncthreads();   // publishes xs (and h/c init on first iteration)

    for (int dt = 0; dt < kTB; ++dt) {
      const int t = t0 + dt;
      const uint4* __restrict__ xp0  = reinterpret_cast<const uint4*>(&xs[dt][0][0]);
      const uint4* __restrict__ xp1  = reinterpret_cast<const uint4*>(&xs[dt][1][0]);
      const uint4* __restrict__ h1p0 = reinterpret_cast<const uint4*>(&h1buf[(t+1)&1][0][0]);
      const uint4* __restrict__ h1p1 = reinterpret_cast<const uint4*>(&h1buf[(t+1)&1][1][0]);
      const uint4* __restrict__ h2p0 = reinterpret_cast<const uint4*>(&h2buf[t&1][0][0]);
      const uint4* __restrict__ h2p1 = reinterpret_cast<const uint4*>(&h2buf[t&1][1][0]);

      float a1_0 = bias1, a1_1 = bias1, a2_0 = bias2, a2_1 = bias2;

      // x part: 8 uint4 (32 half2) per chain -> 32 dot2 per chain
#pragma unroll
      for (int p = 0; p < 8; ++p) {
        const uint4 v0 = xp0[p], v1 = xp1[p];
        a1_0 = dot2u(wx1[4*p+0], v0.x, a1_0); a1_1 = dot2u(wx1[4*p+0], v1.x, a1_1);
        a1_0 = dot2u(wx1[4*p+1], v0.y, a1_0); a1_1 = dot2u(wx1[4*p+1], v1.y, a1_1);
        a1_0 = dot2u(wx1[4*p+2], v0.z, a1_0); a1_1 = dot2u(wx1[4*p+2], v1.z, a1_1);
        a1_0 = dot2u(wx1[4*p+3], v0.w, a1_0); a1_1 = dot2u(wx1[4*p+3], v1.w, a1_1);
      }
      // h1 part: read once, feed both Wh1 (->a1) and Wx2 (->a2)
#pragma unroll
      for (int p = 0; p < 16; ++p) {
        const uint4 v0 = h1p0[p], v1 = h1p1[p];
        a1_0 = dot2u(wh1[4*p+0], v0.x, a1_0); a1_1 = dot2u(wh1[4*p+0], v1.x, a1_1);
        a2_0 = dot2u(wx2[4*p+0], v0.x, a2_0); a2_1 = dot2u(wx2[4*p+0], v1.x, a2_1);
        a1_0 = dot2u(wh1[4*p+1], v0.y, a1_0); a1_1 = dot2u(wh1[4*p+1], v1.y, a1_1);
        a2_0 = dot2u(wx2[4*p+1], v0.y, a2_0); a2_1 = dot2u(wx2[4*p+1], v1.y, a2_1);
        a1_0 = dot2u(wh1[4*p+2], v0.z, a1_0); a1_1 = dot2u(wh1[4*p+2], v1.z, a1_1);
        a2_0 = dot2u(wx2[4*p+2], v0.z, a2_0); a2_1 = dot2u(wx2[4*p+2], v1.z, a2_1);
        a1_0 = dot2u(wh1[4*p+3], v0.w, a1_0); a1_1 = dot2u(wh1[4*p+3], v1.w, a1_1);
        a2_0 = dot2u(wx2[4*p+3], v0.w, a2_0); a2_1 = dot2u(wx2[4*p+3], v1.w, a2_1);
      }
      // h2 part: Wh2 -> a2
#pragma unroll
      for (int p = 0; p < 16; ++p) {
        const uint4 v0 = h2p0[p], v1 = h2p1[p];
        a2_0 = dot2u(wh2[4*p+0], v0.x, a2_0); a2_1 = dot2u(wh2[4*p+0], v1.x, a2_1);
        a2_0 = dot2u(wh2[4*p+1], v0.y, a2_0); a2_1 = dot2u(wh2[4*p+1], v1.y, a2_1);
        a2_0 = dot2u(wh2[4*p+2], v0.z, a2_0); a2_1 = dot2u(wh2[4*p+2], v1.z, a2_1);
        a2_0 = dot2u(wh2[4*p+3], v0.w, a2_0); a2_1 = dot2u(wh2[4*p+3], v1.w, a2_1);
      }
      g1[0][tid] = a1_0; g1[1][tid] = a1_1;
      g2[0][tid] = a2_0; g2[1][tid] = a2_1;
      __syncthreads();

      if (tid < 256) {                   // layer-1 cells -> h1(t)
        const int cc = tid >> 7, j = tid & 127;
        const float gi = g1[cc][j], gf = g1[cc][j+128];
        const float gg = g1[cc][j+256], go = g1[cc][j+384];
        cst = sigf(gf) * cst + sigf(gi) * tanhff(gg);
        reinterpret_cast<__half*>(&h1buf[t & 1][cc][0])[j] =
            __float2half_rn(sigf(go) * tanhff(cst));
      } else if (t > 0) {                // layer-2 cells -> h2(t-1)
        const int cc = (tid >> 7) & 1, j = tid & 127;
        const float gi = g2[cc][j], gf = g2[cc][j+128];
        const float gg = g2[cc][j+256], go = g2[cc][j+384];
        cst = sigf(gf) * cst + sigf(gi) * tanhff(gg);
        reinterpret_cast<__half*>(&h2buf[(t + 1) & 1][cc][0])[j] =
            __float2half_rn(sigf(go) * tanhff(cst));
      }
      __syncthreads();
    }
  }

  // epilogue: gates2(1023) from h1(1023)=h1buf[1], h2(1022)=h2buf[0]
  {
    const uint4* __restrict__ h1p0 = reinterpret_cast<const uint4*>(&h1buf[1][0][0]);
    const uint4* __restrict__ h1p1 = reinterpret_cast<const uint4*>(&h1buf[1][1][0]);
    const uint4* __restrict__ h2p0 = reinterpret_cast<const uint4*>(&h2buf[0][0][0]);
    const uint4* __restrict__ h2p1 = reinterpret_cast<const uint4*>(&h2buf[0][1][0]);
    float a2_0 = bias2, a2_1 = bias2;
#pragma unroll
    for (int p = 0; p < 16; ++p) {
      const uint4 v0 = h1p0[p], v1 = h1p1[p];
      a2_0 = dot2u(wx2[4*p+0], v0.x, a2_0); a2_1 = dot2u(wx2[4*p+0], v1.x, a2_1);
      a2_0 = dot2u(wx2[4*p+1], v0.y, a2_0); a2_1 = dot2u(wx2[4*p+1], v1.y, a2_1);
      a2_0 = dot2u(wx2[4*p+2], v0.z, a2_0); a2_1 = dot2u(wx2[4*p+2], v1.z, a2_1);
      a2_0 = dot2u(wx2[4*p+3], v0.w, a2_0); a2_1 = dot2u(wx2[4*p+3], v1.w, a2_1);
      const uint4 u0 = h2p0[p], u1 = h2p1[p];
      a2_0 = dot2u(wh2[4*p+0], u0.x, a2_0); a2_1 = dot2u(wh2[4*p+0], u1.x, a2_1);
      a2_0 = dot2u(wh2[4*p+1], u0.y, a2_0); a2_1 = dot2u(wh2[4*p+1], u1.y, a2_1);
      a2_0 = dot2u(wh2[4*p+2], u0.z, a2_0); a2_1 = dot2u(wh2[4*p+2], u1.z, a2_1);
      a2_0 = dot2u(wh2[4*p+3], u0.w, a2_0); a2_1 = dot2u(wh2[4*p+3], u1.w, a2_1);
    }
    g2[0][tid] = a2_0; g2[1][tid] = a2_1;
    __syncthreads();
    if (tid >= 256) {
      const int cc = (tid >> 7) & 1, j = tid & 127;
      const float gi = g2[cc][j], gf = g2[cc][j+128];
      const float gg = g2[cc][j+256], go = g2[cc][j+384];
      cst = sigf(gf) * cst + sigf(gi) * tanhff(gg);
      hfin[cc][j] = sigf(go) * tanhff(cst);
    }
    __syncthreads();
  }

  // classifier head: logits[b0+c, n] = Wc[n,:] . h2fin[c] + bc[n]
  if (tid < 8) {
    const int n = tid & 3, c = tid >> 2;
    const float* wr = Wc + (size_t)n * kH;
    float s0 = 0.f, s1 = 0.f, s2 = 0.f, s3 = 0.f;
#pragma unroll
    for (int j = 0; j < kH; j += 4) {
      s0 = fmaf(wr[j],   hfin[c][j],   s0);
      s1 = fmaf(wr[j+1], hfin[c][j+1], s1);
      s2 = fmaf(wr[j+2], hfin[c][j+2], s2);
      s3 = fmaf(wr[j+3], hfin[c][j+3], s3);
    }
    out[(size_t)(b0 + c) * 4 + n] = bc[n] + ((s0 + s1) + (s2 + s3));
  }
}

} // namespace

extern "C" void kernel_launch(void* const* d_in, const int* in_sizes, int n_in,
                              void* d_out, int out_size, void* d_ws, size_t ws_size,
                              hipStream_t stream) {
  const float* x   = (const float*)d_in[0];
  const float* Wx1 = (const float*)d_in[1];
  const float* bx1 = (const float*)d_in[2];
  const float* Wh1 = (const float*)d_in[3];
  const float* bh1 = (const float*)d_in[4];
  const float* Wx2 = (const float*)d_in[5];
  const float* bx2 = (const float*)d_in[6];
  const float* Wh2 = (const float*)d_in[7];
  const float* bh2 = (const float*)d_in[8];
  const float* Wc  = (const float*)d_in[9];
  const float* bc  = (const float*)d_in[10];

  hipLaunchKernelGGL(lstm_fused, dim3(256), dim3(512), 0, stream,
                     x, Wx1, bx1, Wh1, bh1, Wx2, bx2, Wh2, bh2, Wc, bc,
                     (float*)d_out);
}

// Round 4
// 3633.403 us; speedup vs baseline: 13.0214x; 1.2964x over previous
//
#include <hip/hip_runtime.h>
#include <hip/hip_fp16.h>

namespace {

constexpr int kS  = 1024;   // SEQ
constexpr int kI  = 64;     // INPUT_SIZE
constexpr int kH  = 128;    // HIDDEN
constexpr int kG  = 512;    // 4*HIDDEN
constexpr int kTB = 8;      // timestep tile

typedef _Float16 h2v __attribute__((ext_vector_type(2)));

__device__ __forceinline__ float dot2u(unsigned a, unsigned b, float c) {
#if __has_builtin(__builtin_amdgcn_fdot2)
  return __builtin_amdgcn_fdot2(__builtin_bit_cast(h2v, a),
                                __builtin_bit_cast(h2v, b), c, false);
#else
  __half2 ah = __builtin_bit_cast(__half2, a);
  __half2 bh = __builtin_bit_cast(__half2, b);
  c = fmaf(__half2float(__low2half(ah)),  __half2float(__low2half(bh)),  c);
  c = fmaf(__half2float(__high2half(ah)), __half2float(__high2half(bh)), c);
  return c;
#endif
}

__device__ __forceinline__ unsigned packh2(float lo, float hi) {
  __half2 h = __floats2half2_rn(lo, hi);
  return __builtin_bit_cast(unsigned, h);
}

__device__ __forceinline__ float rcpf(float x) {
#if __has_builtin(__builtin_amdgcn_rcpf)
  return __builtin_amdgcn_rcpf(x);
#else
  return 1.0f / x;
#endif
}
__device__ __forceinline__ float sigf(float x)  { return rcpf(1.0f + __expf(-x)); }
__device__ __forceinline__ float tanhff(float x){ return 1.0f - 2.0f * rcpf(1.0f + __expf(2.0f * x)); }

// Fused 2-layer LSTM + head. 256 blocks x 512 threads; block handles chains
// b0, b0+1. Thread tid owns gate row tid of both layers' recurrent weights
// (wh1/wx2/wh2 = 192 packed-fp16 VGPRs, resident). The x-projection uses a
// tile-local wx1p[32] whose live range is only the projection phase; its
// results (bias1 + Wx1 x(t)) are parked as fp32 in LDS (self-read only).
// Register budget: amdgpu_waves_per_eu(2,2) -> allocator targets 2 waves/SIMD,
// up to 256 VGPRs (512-thread block caps at 256 anyway).
__global__ __launch_bounds__(512) __attribute__((amdgpu_waves_per_eu(2, 2)))
void lstm_fused(
    const float* __restrict__ x,
    const float* __restrict__ Wx1, const float* __restrict__ bx1,
    const float* __restrict__ Wh1, const float* __restrict__ bh1,
    const float* __restrict__ Wx2, const float* __restrict__ bx2,
    const float* __restrict__ Wh2, const float* __restrict__ bh2,
    const float* __restrict__ Wc,  const float* __restrict__ bc,
    float* __restrict__ out)
{
  const int tid = threadIdx.x;
  const int b0  = blockIdx.x * 2;

  __shared__ __align__(16) unsigned xs[kTB][2][kI/2];    // 2 KiB  staged x (fp16)
  __shared__ float xg[kTB][2][kG];                       // 32 KiB x-projection (fp32)
  __shared__ __align__(16) unsigned h1buf[2][2][kH/2];   // 1 KiB  double-buffered h1
  __shared__ __align__(16) unsigned h2buf[2][2][kH/2];   // 1 KiB  double-buffered h2
  __shared__ float g1[2][kG];                            // 2 KiB  gate preacts L1
  __shared__ float g2[2][kG];                            // 2 KiB  gate preacts L2
  __shared__ float hfin[2][kH];                          // final h2 (fp32)

  // ---- resident recurrent weights for gate row tid (packed fp16) ----
  unsigned wh1[kH/2], wx2[kH/2], wh2[kH/2];
  {
    const float4* q = reinterpret_cast<const float4*>(Wh1 + (size_t)tid * kH);
    const float4* r = reinterpret_cast<const float4*>(Wx2 + (size_t)tid * kH);
    const float4* s = reinterpret_cast<const float4*>(Wh2 + (size_t)tid * kH);
#pragma unroll
    for (int i = 0; i < kH/4; ++i) {
      float4 v = q[i]; wh1[2*i] = packh2(v.x, v.y); wh1[2*i+1] = packh2(v.z, v.w);
      float4 w = r[i]; wx2[2*i] = packh2(w.x, w.y); wx2[2*i+1] = packh2(w.z, w.w);
      float4 u = s[i]; wh2[2*i] = packh2(u.x, u.y); wh2[2*i+1] = packh2(u.z, u.w);
    }
  }
  const float bias1 = bx1[tid] + bh1[tid];
  const float bias2 = bx2[tid] + bh2[tid];

  // zero-init both h double buffers (256 + 256 unsigned)
  if (tid < 256) reinterpret_cast<unsigned*>(h1buf)[tid]       = 0u;
  else           reinterpret_cast<unsigned*>(h2buf)[tid - 256] = 0u;
  float cst = 0.0f;   // c1 for tid<256 (chain tid>>7), c2 for tid>=256

  for (int t0 = 0; t0 < kS; t0 += kTB) {
    // ---- stage x[b0..b0+1][t0..t0+7][:] -> fp16 LDS (256 float4, tid<256) ----
    if (tid < 256) {
      const int dt = tid >> 5, c = (tid >> 4) & 1, i4 = tid & 15;
      const float4 v = *reinterpret_cast<const float4*>(
          x + ((size_t)(b0 + c) * kS + (size_t)(t0 + dt)) * kI + i4 * 4);
      xs[dt][c][i4*2]   = packh2(v.x, v.y);
      xs[dt][c][i4*2+1] = packh2(v.z, v.w);
    }
    __syncthreads();   // publishes xs (and h/c init on first iteration)

    // ---- x-projection: xg[dt][c][tid] = bias1 + Wx1[tid,:] . x(t0+dt, c) ----
    {
      unsigned wx1p[kI/2];             // tile-local; dead after this phase
      const float4* p = reinterpret_cast<const float4*>(Wx1 + (size_t)tid * kI);
#pragma unroll
      for (int i = 0; i < kI/4; ++i) {
        float4 v = p[i]; wx1p[2*i] = packh2(v.x, v.y); wx1p[2*i+1] = packh2(v.z, v.w);
      }
#pragma unroll
      for (int dt = 0; dt < kTB; ++dt) {
        const uint4* x0 = reinterpret_cast<const uint4*>(&xs[dt][0][0]);
        const uint4* x1 = reinterpret_cast<const uint4*>(&xs[dt][1][0]);
        float a0 = bias1, a1 = bias1, a0b = 0.0f, a1b = 0.0f;
#pragma unroll
        for (int p8 = 0; p8 < 8; ++p8) {
          const uint4 v0 = x0[p8], v1 = x1[p8];
          a0  = dot2u(wx1p[4*p8+0], v0.x, a0);  a1  = dot2u(wx1p[4*p8+0], v1.x, a1);
          a0b = dot2u(wx1p[4*p8+1], v0.y, a0b); a1b = dot2u(wx1p[4*p8+1], v1.y, a1b);
          a0  = dot2u(wx1p[4*p8+2], v0.z, a0);  a1  = dot2u(wx1p[4*p8+2], v1.z, a1);
          a0b = dot2u(wx1p[4*p8+3], v0.w, a0b); a1b = dot2u(wx1p[4*p8+3], v1.w, a1b);
        }
        xg[dt][0][tid] = a0 + a0b;     // self-read only -> no barrier needed
        xg[dt][1][tid] = a1 + a1b;
      }
    }

    // ---- recurrent steps ----
    for (int dt = 0; dt < kTB; ++dt) {
      const int t = t0 + dt;
      const uint4* h1p0 = reinterpret_cast<const uint4*>(&h1buf[(t+1)&1][0][0]);
      const uint4* h1p1 = reinterpret_cast<const uint4*>(&h1buf[(t+1)&1][1][0]);
      const uint4* h2p0 = reinterpret_cast<const uint4*>(&h2buf[t&1][0][0]);
      const uint4* h2p1 = reinterpret_cast<const uint4*>(&h2buf[t&1][1][0]);

      float a1_0 = xg[dt][0][tid], a1_1 = xg[dt][1][tid];
      float a2_0 = bias2,          a2_1 = bias2;

      // h1 part: read once (wave-broadcast), feed Wh1 (->a1) and Wx2 (->a2)
#pragma unroll
      for (int p = 0; p < 16; ++p) {
        const uint4 v0 = h1p0[p], v1 = h1p1[p];
        a1_0 = dot2u(wh1[4*p+0], v0.x, a1_0); a1_1 = dot2u(wh1[4*p+0], v1.x, a1_1);
        a2_0 = dot2u(wx2[4*p+0], v0.x, a2_0); a2_1 = dot2u(wx2[4*p+0], v1.x, a2_1);
        a1_0 = dot2u(wh1[4*p+1], v0.y, a1_0); a1_1 = dot2u(wh1[4*p+1], v1.y, a1_1);
        a2_0 = dot2u(wx2[4*p+1], v0.y, a2_0); a2_1 = dot2u(wx2[4*p+1], v1.y, a2_1);
        a1_0 = dot2u(wh1[4*p+2], v0.z, a1_0); a1_1 = dot2u(wh1[4*p+2], v1.z, a1_1);
        a2_0 = dot2u(wx2[4*p+2], v0.z, a2_0); a2_1 = dot2u(wx2[4*p+2], v1.z, a2_1);
        a1_0 = dot2u(wh1[4*p+3], v0.w, a1_0); a1_1 = dot2u(wh1[4*p+3], v1.w, a1_1);
        a2_0 = dot2u(wx2[4*p+3], v0.w, a2_0); a2_1 = dot2u(wx2[4*p+3], v1.w, a2_1);
      }
      // h2 part: Wh2 -> a2
#pragma unroll
      for (int p = 0; p < 16; ++p) {
        const uint4 v0 = h2p0[p], v1 = h2p1[p];
        a2_0 = dot2u(wh2[4*p+0], v0.x, a2_0); a2_1 = dot2u(wh2[4*p+0], v1.x, a2_1);
        a2_0 = dot2u(wh2[4*p+1], v0.y, a2_0); a2_1 = dot2u(wh2[4*p+1], v1.y, a2_1);
        a2_0 = dot2u(wh2[4*p+2], v0.z, a2_0); a2_1 = dot2u(wh2[4*p+2], v1.z, a2_1);
        a2_0 = dot2u(wh2[4*p+3], v0.w, a2_0); a2_1 = dot2u(wh2[4*p+3], v1.w, a2_1);
      }
      g1[0][tid] = a1_0; g1[1][tid] = a1_1;
      g2[0][tid] = a2_0; g2[1][tid] = a2_1;
      __syncthreads();

      if (tid < 256) {                   // layer-1 cells -> h1(t)
        const int cc = tid >> 7, j = tid & 127;
        const float gi = g1[cc][j], gf = g1[cc][j+128];
        const float gg = g1[cc][j+256], go = g1[cc][j+384];
        cst = sigf(gf) * cst + sigf(gi) * tanhff(gg);
        reinterpret_cast<__half*>(&h1buf[t & 1][cc][0])[j] =
            __float2half_rn(sigf(go) * tanhff(cst));
      } else if (t > 0) {                // layer-2 cells -> h2(t-1)
        const int cc = (tid >> 7) & 1, j = tid & 127;
        const float gi = g2[cc][j], gf = g2[cc][j+128];
        const float gg = g2[cc][j+256], go = g2[cc][j+384];
        cst = sigf(gf) * cst + sigf(gi) * tanhff(gg);
        reinterpret_cast<__half*>(&h2buf[(t + 1) & 1][cc][0])[j] =
            __float2half_rn(sigf(go) * tanhff(cst));
      }
      __syncthreads();
    }
  }

  // epilogue: gates2(1023) from h1(1023)=h1buf[1], h2(1022)=h2buf[0]
  {
    const uint4* h1p0 = reinterpret_cast<const uint4*>(&h1buf[1][0][0]);
    const uint4* h1p1 = reinterpret_cast<const uint4*>(&h1buf[1][1][0]);
    const uint4* h2p0 = reinterpret_cast<const uint4*>(&h2buf[0][0][0]);
    const uint4* h2p1 = reinterpret_cast<const uint4*>(&h2buf[0][1][0]);
    float a2_0 = bias2, a2_1 = bias2;
#pragma unroll
    for (int p = 0; p < 16; ++p) {
      const uint4 v0 = h1p0[p], v1 = h1p1[p];
      a2_0 = dot2u(wx2[4*p+0], v0.x, a2_0); a2_1 = dot2u(wx2[4*p+0], v1.x, a2_1);
      a2_0 = dot2u(wx2[4*p+1], v0.y, a2_0); a2_1 = dot2u(wx2[4*p+1], v1.y, a2_1);
      a2_0 = dot2u(wx2[4*p+2], v0.z, a2_0); a2_1 = dot2u(wx2[4*p+2], v1.z, a2_1);
      a2_0 = dot2u(wx2[4*p+3], v0.w, a2_0); a2_1 = dot2u(wx2[4*p+3], v1.w, a2_1);
      const uint4 u0 = h2p0[p], u1 = h2p1[p];
      a2_0 = dot2u(wh2[4*p+0], u0.x, a2_0); a2_1 = dot2u(wh2[4*p+0], u1.x, a2_1);
      a2_0 = dot2u(wh2[4*p+1], u0.y, a2_0); a2_1 = dot2u(wh2[4*p+1], u1.y, a2_1);
      a2_0 = dot2u(wh2[4*p+2], u0.z, a2_0); a2_1 = dot2u(wh2[4*p+2], u1.z, a2_1);
      a2_0 = dot2u(wh2[4*p+3], u0.w, a2_0); a2_1 = dot2u(wh2[4*p+3], u1.w, a2_1);
    }
    g2[0][tid] = a2_0; g2[1][tid] = a2_1;
    __syncthreads();
    if (tid >= 256) {
      const int cc = (tid >> 7) & 1, j = tid & 127;
      const float gi = g2[cc][j], gf = g2[cc][j+128];
      const float gg = g2[cc][j+256], go = g2[cc][j+384];
      cst = sigf(gf) * cst + sigf(gi) * tanhff(gg);
      hfin[cc][j] = sigf(go) * tanhff(cst);
    }
    __syncthreads();
  }

  // classifier head: logits[b0+c, n] = Wc[n,:] . h2fin[c] + bc[n]
  if (tid < 8) {
    const int n = tid & 3, c = tid >> 2;
    const float* wr = Wc + (size_t)n * kH;
    float s0 = 0.f, s1 = 0.f, s2 = 0.f, s3 = 0.f;
#pragma unroll
    for (int j = 0; j < kH; j += 4) {
      s0 = fmaf(wr[j],   hfin[c][j],   s0);
      s1 = fmaf(wr[j+1], hfin[c][j+1], s1);
      s2 = fmaf(wr[j+2], hfin[c][j+2], s2);
      s3 = fmaf(wr[j+3], hfin[c][j+3], s3);
    }
    out[(size_t)(b0 + c) * 4 + n] = bc[n] + ((s0 + s1) + (s2 + s3));
  }
}

} // namespace

extern "C" void kernel_launch(void* const* d_in, const int* in_sizes, int n_in,
                              void* d_out, int out_size, void* d_ws, size_t ws_size,
                              hipStream_t stream) {
  const float* x   = (const float*)d_in[0];
  const float* Wx1 = (const float*)d_in[1];
  const float* bx1 = (const float*)d_in[2];
  const float* Wh1 = (const float*)d_in[3];
  const float* bh1 = (const float*)d_in[4];
  const float* Wx2 = (const float*)d_in[5];
  const float* bx2 = (const float*)d_in[6];
  const float* Wh2 = (const float*)d_in[7];
  const float* bh2 = (const float*)d_in[8];
  const float* Wc  = (const float*)d_in[9];
  const float* bc  = (const float*)d_in[10];

  hipLaunchKernelGGL(lstm_fused, dim3(256), dim3(512), 0, stream,
                     x, Wx1, bx1, Wh1, bh1, Wx2, bx2, Wh2, bh2, Wc, bc,
                     (float*)d_out);
}

// Round 5
// 3520.166 us; speedup vs baseline: 13.4402x; 1.0322x over previous
//
#include <hip/hip_runtime.h>
#include <hip/hip_fp16.h>

namespace {

constexpr int kS  = 1024;   // SEQ
constexpr int kI  = 64;     // INPUT_SIZE
constexpr int kH  = 128;    // HIDDEN
constexpr int kG  = 512;    // 4*HIDDEN
constexpr int kTB1 = 8;     // K1 x staging tile (steps)
constexpr int kTB2 = 8;     // K2 h1 staging tile (steps)

typedef _Float16 h2v __attribute__((ext_vector_type(2)));

__device__ __forceinline__ float dot2u(unsigned a, unsigned b, float c) {
#if __has_builtin(__builtin_amdgcn_fdot2)
  return __builtin_amdgcn_fdot2(__builtin_bit_cast(h2v, a),
                                __builtin_bit_cast(h2v, b), c, false);
#else
  __half2 ah = __builtin_bit_cast(__half2, a);
  __half2 bh = __builtin_bit_cast(__half2, b);
  c = fmaf(__half2float(__low2half(ah)),  __half2float(__low2half(bh)),  c);
  c = fmaf(__half2float(__high2half(ah)), __half2float(__high2half(bh)), c);
  return c;
#endif
}

__device__ __forceinline__ unsigned packh2(float lo, float hi) {
  __half2 h = __floats2half2_rn(lo, hi);
  return __builtin_bit_cast(unsigned, h);
}

__device__ __forceinline__ float rcpf(float x) {
#if __has_builtin(__builtin_amdgcn_rcpf)
  return __builtin_amdgcn_rcpf(x);
#else
  return 1.0f / x;
#endif
}
__device__ __forceinline__ float sigf(float x)  { return rcpf(1.0f + __expf(-x)); }
__device__ __forceinline__ float tanhff(float x){ return 1.0f - 2.0f * rcpf(1.0f + __expf(2.0f * x)); }

// ---------------- K1: layer-1 LSTM, 1 chain/block ----------------
// 512 blocks x 512 thr -> 2 blocks/CU co-resident (barrier hiding).
// Thread tid owns gate row tid: Wx1 row (32 regs) + Wh1 row (64 regs) ~ 96
// weight VGPRs + ~25 overhead: fits the compiler's 128-reg / 4-waves-per-EU
// sweet spot with NO spills.
__global__ __launch_bounds__(512) void lstm_l1(
    const float* __restrict__ x, const float* __restrict__ Wx1,
    const float* __restrict__ bx1, const float* __restrict__ Wh1,
    const float* __restrict__ bh1, __half* __restrict__ h1out)
{
  const int tid = threadIdx.x;
  const int b   = blockIdx.x;

  __shared__ __align__(16) unsigned xs[kTB1][kI/2];   // 1 KiB staged x (fp16)
  __shared__ __align__(16) unsigned h1b[2][kH/2];     // 512 B dbuf h1
  __shared__ float g[kG];                             // 2 KiB gate preacts

  unsigned wx1[kI/2], wh1r[kH/2];
  {
    const float4* p = reinterpret_cast<const float4*>(Wx1 + (size_t)tid * kI);
#pragma unroll
    for (int i = 0; i < kI/4; ++i) {
      float4 v = p[i]; wx1[2*i] = packh2(v.x, v.y); wx1[2*i+1] = packh2(v.z, v.w);
    }
    const float4* q = reinterpret_cast<const float4*>(Wh1 + (size_t)tid * kH);
#pragma unroll
    for (int i = 0; i < kH/4; ++i) {
      float4 v = q[i]; wh1r[2*i] = packh2(v.x, v.y); wh1r[2*i+1] = packh2(v.z, v.w);
    }
  }
  const float bias = bx1[tid] + bh1[tid];

  if (tid < kH/2) h1b[1][tid] = 0u;   // h(-1) lives in buf[(0+1)&1] = buf 1
  float cst = 0.0f;

  for (int t0 = 0; t0 < kS; t0 += kTB1) {
    if (tid < 128) {                  // stage 8 steps of x (128 float4)
      const int dt = tid >> 4, i4 = tid & 15;
      const float4 v = *reinterpret_cast<const float4*>(
          x + ((size_t)b * kS + (size_t)(t0 + dt)) * kI + i4 * 4);
      xs[dt][i4*2]   = packh2(v.x, v.y);
      xs[dt][i4*2+1] = packh2(v.z, v.w);
    }
    __syncthreads();

    for (int dt = 0; dt < kTB1; ++dt) {
      const int t = t0 + dt;
      const uint4* xp = reinterpret_cast<const uint4*>(&xs[dt][0]);
      const uint4* hp = reinterpret_cast<const uint4*>(&h1b[(t+1)&1][0]);
      float a0 = bias, a1 = 0.f, a2 = 0.f, a3 = 0.f;
#pragma unroll
      for (int p = 0; p < 8; ++p) {
        const uint4 v = xp[p];
        a0 = dot2u(wx1[4*p+0], v.x, a0); a1 = dot2u(wx1[4*p+1], v.y, a1);
        a2 = dot2u(wx1[4*p+2], v.z, a2); a3 = dot2u(wx1[4*p+3], v.w, a3);
      }
#pragma unroll
      for (int p = 0; p < 16; ++p) {
        const uint4 v = hp[p];
        a0 = dot2u(wh1r[4*p+0], v.x, a0); a1 = dot2u(wh1r[4*p+1], v.y, a1);
        a2 = dot2u(wh1r[4*p+2], v.z, a2); a3 = dot2u(wh1r[4*p+3], v.w, a3);
      }
      g[tid] = (a0 + a1) + (a2 + a3);
      __syncthreads();
      if (tid < kH) {
        const float gi = g[tid], gf = g[tid+128], gg = g[tid+256], go = g[tid+384];
        cst = sigf(gf) * cst + sigf(gi) * tanhff(gg);
        const float h = sigf(go) * tanhff(cst);
        const __half hh = __float2half_rn(h);
        reinterpret_cast<__half*>(&h1b[t & 1][0])[tid] = hh;
        h1out[((size_t)b * kS + (size_t)t) * kH + tid] = hh;
      }
      __syncthreads();
    }
  }
}

// ---------------- K2: layer-2 LSTM + head, 2 chains/block ----------------
// 256 blocks x 512 thr, 1 block/CU (LDS 138 KiB). Wx2 row resident (64 regs);
// Wh2 streamed from LDS, XOR-swizzled to break the stride-256B row-read
// conflict (naive = all lanes same bank; swizzled ~4-way, hidden under VALU).
__global__ __launch_bounds__(512) void lstm_l2(
    const __half* __restrict__ h1in,
    const float* __restrict__ Wx2, const float* __restrict__ bx2,
    const float* __restrict__ Wh2, const float* __restrict__ bh2,
    const float* __restrict__ Wc,  const float* __restrict__ bc,
    float* __restrict__ out)
{
  const int tid = threadIdx.x;
  const int b0  = blockIdx.x * 2;

  __shared__ __align__(16) unsigned whl[kG * kH / 2];   // 128 KiB Wh2 (swizzled)
  __shared__ __align__(16) unsigned hs[kTB2][2][kH/2];  // 4 KiB staged h1
  __shared__ __align__(16) unsigned h2b[2][2][kH/2];    // 1 KiB dbuf h2
  __shared__ float g[2][kG];                            // 4 KiB gate preacts
  __shared__ float hfin[2][kH];                         // 1 KiB final h2

  unsigned wx2[kH/2];
  {
    const float4* p = reinterpret_cast<const float4*>(Wx2 + (size_t)tid * kH);
#pragma unroll
    for (int i = 0; i < kH/4; ++i) {
      float4 v = p[i]; wx2[2*i] = packh2(v.x, v.y); wx2[2*i+1] = packh2(v.z, v.w);
    }
  }
  const float bias = bx2[tid] + bh2[tid];

  // Wh2 -> LDS fp16, swizzled: row r, 16B-chunk c16 at byte r*256 + (c16*16 ^ ((r&15)*16))
#pragma unroll
  for (int i = 0; i < 16; ++i) {
    const int idx = i * 512 + tid;        // 8192 16-byte chunks
    const int r = idx >> 4, c16 = idx & 15;
    const float4 vA = *reinterpret_cast<const float4*>(Wh2 + (size_t)r * kH + c16 * 8);
    const float4 vB = *reinterpret_cast<const float4*>(Wh2 + (size_t)r * kH + c16 * 8 + 4);
    uint4 w;
    w.x = packh2(vA.x, vA.y); w.y = packh2(vA.z, vA.w);
    w.z = packh2(vB.x, vB.y); w.w = packh2(vB.z, vB.w);
    *reinterpret_cast<uint4*>(reinterpret_cast<char*>(whl) + r * 256 +
                              ((c16 << 4) ^ ((r & 15) << 4))) = w;
  }
  if (tid < 128) reinterpret_cast<unsigned*>(&h2b[1][0][0])[tid] = 0u;  // h2(-1)
  float cst = 0.0f;
  __syncthreads();

  for (int t0 = 0; t0 < kS; t0 += kTB2) {
    if (tid < 256) {                     // stage 8 steps x 2 chains of h1
      const int c = tid >> 7, dt = (tid >> 4) & 7, u = tid & 15;
      reinterpret_cast<uint4*>(&hs[dt][c][0])[u] =
          reinterpret_cast<const uint4*>(
              h1in + ((size_t)(b0 + c) * kS + (size_t)(t0 + dt)) * kH)[u];
    }
    __syncthreads();

    for (int dt = 0; dt < kTB2; ++dt) {
      const int t = t0 + dt;
      const uint4* hA = reinterpret_cast<const uint4*>(&hs[dt][0][0]);
      const uint4* hB = reinterpret_cast<const uint4*>(&hs[dt][1][0]);
      const uint4* pA = reinterpret_cast<const uint4*>(&h2b[(t+1)&1][0][0]);
      const uint4* pB = reinterpret_cast<const uint4*>(&h2b[(t+1)&1][1][0]);
      const char* wrow = reinterpret_cast<const char*>(whl) + tid * 256;
      const int swz = (tid & 15) << 4;

      float A0 = bias, A1 = 0.f, A2 = 0.f, A3 = 0.f;
      float B0 = bias, B1 = 0.f, B2 = 0.f, B3 = 0.f;
#pragma unroll
      for (int p = 0; p < 16; ++p) {     // Wx2 . h1(t)  (h1 broadcast reads)
        const uint4 vA = hA[p], vB = hB[p];
        A0 = dot2u(wx2[4*p+0], vA.x, A0); B0 = dot2u(wx2[4*p+0], vB.x, B0);
        A1 = dot2u(wx2[4*p+1], vA.y, A1); B1 = dot2u(wx2[4*p+1], vB.y, B1);
        A2 = dot2u(wx2[4*p+2], vA.z, A2); B2 = dot2u(wx2[4*p+2], vB.z, B2);
        A3 = dot2u(wx2[4*p+3], vA.w, A3); B3 = dot2u(wx2[4*p+3], vB.w, B3);
      }
#pragma unroll
      for (int q = 0; q < 16; ++q) {     // Wh2 . h2(t-1)  (swizzled row stream)
        const uint4 w  = *reinterpret_cast<const uint4*>(wrow + ((q << 4) ^ swz));
        const uint4 vA = pA[q], vB = pB[q];
        A0 = dot2u(w.x, vA.x, A0); B0 = dot2u(w.x, vB.x, B0);
        A1 = dot2u(w.y, vA.y, A1); B1 = dot2u(w.y, vB.y, B1);
        A2 = dot2u(w.z, vA.z, A2); B2 = dot2u(w.z, vB.z, B2);
        A3 = dot2u(w.w, vA.w, A3); B3 = dot2u(w.w, vB.w, B3);
      }
      g[0][tid] = (A0 + A1) + (A2 + A3);
      g[1][tid] = (B0 + B1) + (B2 + B3);
      __syncthreads();

      if (tid < 256) {
        const int cc = tid >> 7, j = tid & 127;
        const float gi = g[cc][j], gf = g[cc][j+128];
        const float gg = g[cc][j+256], go = g[cc][j+384];
        cst = sigf(gf) * cst + sigf(gi) * tanhff(gg);
        const float h = sigf(go) * tanhff(cst);
        reinterpret_cast<__half*>(&h2b[t & 1][cc][0])[j] = __float2half_rn(h);
        if (t == kS - 1) hfin[cc][j] = h;
      }
      __syncthreads();
    }
  }

  // classifier head
  if (tid < 8) {
    const int n = tid & 3, c = tid >> 2;
    const float* wr = Wc + (size_t)n * kH;
    float s0 = 0.f, s1 = 0.f, s2 = 0.f, s3 = 0.f;
#pragma unroll
    for (int j = 0; j < kH; j += 4) {
      s0 = fmaf(wr[j],   hfin[c][j],   s0);
      s1 = fmaf(wr[j+1], hfin[c][j+1], s1);
      s2 = fmaf(wr[j+2], hfin[c][j+2], s2);
      s3 = fmaf(wr[j+3], hfin[c][j+3], s3);
    }
    out[(size_t)(b0 + c) * 4 + n] = bc[n] + ((s0 + s1) + (s2 + s3));
  }
}

} // namespace

extern "C" void kernel_launch(void* const* d_in, const int* in_sizes, int n_in,
                              void* d_out, int out_size, void* d_ws, size_t ws_size,
                              hipStream_t stream) {
  const float* x   = (const float*)d_in[0];
  const float* Wx1 = (const float*)d_in[1];
  const float* bx1 = (const float*)d_in[2];
  const float* Wh1 = (const float*)d_in[3];
  const float* bh1 = (const float*)d_in[4];
  const float* Wx2 = (const float*)d_in[5];
  const float* bx2 = (const float*)d_in[6];
  const float* Wh2 = (const float*)d_in[7];
  const float* bh2 = (const float*)d_in[8];
  const float* Wc  = (const float*)d_in[9];
  const float* bc  = (const float*)d_in[10];

  __half* h1 = (__half*)d_ws;   // 512*1024*128 fp16 = 128 MiB layer-1 stream

  hipLaunchKernelGGL(lstm_l1, dim3(512), dim3(512), 0, stream,
                     x, Wx1, bx1, Wh1, bh1, h1);
  hipLaunchKernelGGL(lstm_l2, dim3(256), dim3(512), 0, stream,
                     h1, Wx2, bx2, Wh2, bh2, Wc, bc, (float*)d_out);
}

// Round 7
// 1858.414 us; speedup vs baseline: 25.4582x; 1.8942x over previous
//
#include <hip/hip_runtime.h>
#include <hip/hip_fp16.h>

namespace {

constexpr int kS = 1024;   // SEQ
constexpr int kI = 64;     // INPUT_SIZE
constexpr int kH = 128;    // HIDDEN

typedef _Float16 f16x8 __attribute__((ext_vector_type(8)));
typedef float    f32x4 __attribute__((ext_vector_type(4)));

#define MFMA16(a, b, c) __builtin_amdgcn_mfma_f32_16x16x32_f16((a), (b), (c), 0, 0, 0)

__device__ __forceinline__ float rcpf(float x) {
#if __has_builtin(__builtin_amdgcn_rcpf)
  return __builtin_amdgcn_rcpf(x);
#else
  return 1.0f / x;
#endif
}
__device__ __forceinline__ float sigf(float x)  { return rcpf(1.0f + __expf(-x)); }
__device__ __forceinline__ float tanhff(float x){ return 1.0f - 2.0f * rcpf(1.0f + __expf(2.0f * x)); }

// Load an A fragment: lane holds row (fixed per lane) x 8 consecutive k.
// A and B both use the same (q,j)->k packing, so the true HW k-permutation
// cancels between them; only the verified C/D mapping (col=lane&15,
// row=(lane>>4)*4+reg) is load-bearing.
__device__ __forceinline__ f16x8 afrag(const float* __restrict__ W, int row,
                                       int k0, int ld) {
  const float4* p = reinterpret_cast<const float4*>(W + (size_t)row * ld + k0);
  const float4 u = p[0], v = p[1];
  f16x8 a;
  a[0] = (_Float16)u.x; a[1] = (_Float16)u.y; a[2] = (_Float16)u.z; a[3] = (_Float16)u.w;
  a[4] = (_Float16)v.x; a[5] = (_Float16)v.y; a[6] = (_Float16)v.z; a[7] = (_Float16)v.w;
  return a;
}

// ---------------- K1: layer-1 via MFMA ----------------
// 256 blocks x 1024 thr (16 waves). Block owns chains b0,b0+1 (B cols 0,1;
// cols 2..15 padding read a shared zero slot). Wave w owns gate rows
// [32w,32w+32) as 2 M-tiles; A frags (Wx1:2 + Wh1:4 K-tiles) resident = 48 VGPR.
__global__ __launch_bounds__(1024) void lstm_l1(
    const float* __restrict__ x, const float* __restrict__ Wx1,
    const float* __restrict__ bx1, const float* __restrict__ Wh1,
    const float* __restrict__ bh1, _Float16* __restrict__ h1out)
{
  const int tid  = threadIdx.x;
  const int b0   = blockIdx.x * 2;
  const int w    = tid >> 6;          // wave 0..15
  const int q    = (tid >> 4) & 3;    // k-group within wave
  const int n    = tid & 15;          // B col / D col
  const bool real = (n < 2);

  __shared__ __align__(16) _Float16 xB[8][8][2][8];    // [t][kchunk][n][k&7] 2 KiB
  __shared__ __align__(16) _Float16 hB[2][16][2][8];   // [par][kchunk][n][k&7] 1 KiB
  __shared__ __align__(16) float    zslot[4];          // shared zero line
  __shared__ float gbuf[2][512];                       // gate preacts (real cols)

  f16x8 A[2][6];
  {
    const int rb = w * 32 + (tid & 15);
#pragma unroll
    for (int s = 0; s < 2; ++s) {
      const int row = rb + s * 16;
      A[s][0] = afrag(Wx1, row, q * 8,       kI);
      A[s][1] = afrag(Wx1, row, 32 + q * 8,  kI);
#pragma unroll
      for (int kt = 0; kt < 4; ++kt)
        A[s][2 + kt] = afrag(Wh1, row, kt * 32 + q * 8, kH);
    }
  }

  float bI = 0.f, bF = 0.f, bG = 0.f, bO = 0.f, cst = 0.f;
  if (tid < 256) {
    const int j = tid & 127;
    bI = bx1[j]       + bh1[j];
    bF = bx1[j + 128] + bh1[j + 128];
    bG = bx1[j + 256] + bh1[j + 256];
    bO = bx1[j + 384] + bh1[j + 384];
  }
  if (tid < 256)      reinterpret_cast<_Float16*>(hB)[tid] = (_Float16)0.f; // hB[0]=0
  else if (tid < 260) zslot[tid - 256] = 0.f;

  const int   off = q * 32 + n * 16;
  const char* zp  = reinterpret_cast<const char*>(zslot);

  for (int t0 = 0; t0 < kS; t0 += 8) {
    {  // stage x[b0..b0+1][t0..t0+7][:] -> B-fragment layout (fp16)
      const int st = tid >> 7, sn = (tid >> 6) & 1, sk = tid & 63;
      const float v = x[((size_t)(b0 + sn) * kS + (size_t)(t0 + st)) * kI + sk];
      xB[st][sk >> 3][sn][sk & 7] = (_Float16)v;
    }
    __syncthreads();

    for (int dt = 0; dt < 8; ++dt) {
      const int t = t0 + dt;
      const char* xb = reinterpret_cast<const char*>(&xB[dt][0][0][0]);
      const char* hb = reinterpret_cast<const char*>(&hB[t & 1][0][0][0]);
      const f16x8 bf0 = *reinterpret_cast<const f16x8*>(real ? xb + off       : zp);
      const f16x8 bf1 = *reinterpret_cast<const f16x8*>(real ? xb + 128 + off : zp);
      const f16x8 bf2 = *reinterpret_cast<const f16x8*>(real ? hb + off       : zp);
      const f16x8 bf3 = *reinterpret_cast<const f16x8*>(real ? hb + 128 + off : zp);
      const f16x8 bf4 = *reinterpret_cast<const f16x8*>(real ? hb + 256 + off : zp);
      const f16x8 bf5 = *reinterpret_cast<const f16x8*>(real ? hb + 384 + off : zp);

      f32x4 d0 = {0.f, 0.f, 0.f, 0.f}, d1 = {0.f, 0.f, 0.f, 0.f};
      d0 = MFMA16(A[0][0], bf0, d0);  d1 = MFMA16(A[1][0], bf0, d1);
      d0 = MFMA16(A[0][1], bf1, d0);  d1 = MFMA16(A[1][1], bf1, d1);
      d0 = MFMA16(A[0][2], bf2, d0);  d1 = MFMA16(A[1][2], bf2, d1);
      d0 = MFMA16(A[0][3], bf3, d0);  d1 = MFMA16(A[1][3], bf3, d1);
      d0 = MFMA16(A[0][4], bf4, d0);  d1 = MFMA16(A[1][4], bf4, d1);
      d0 = MFMA16(A[0][5], bf5, d0);  d1 = MFMA16(A[1][5], bf5, d1);

      if (real) {   // D col n, rows 32w+16s+4q..+3
        *reinterpret_cast<f32x4*>(&gbuf[n][w * 32 + q * 4])      = d0;
        *reinterpret_cast<f32x4*>(&gbuf[n][w * 32 + 16 + q * 4]) = d1;
      }
      __syncthreads();

      if (tid < 256) {
        const int cc = tid >> 7, j = tid & 127;
        const float gi = gbuf[cc][j]       + bI;
        const float gf = gbuf[cc][j + 128] + bF;
        const float gg = gbuf[cc][j + 256] + bG;
        const float go = gbuf[cc][j + 384] + bO;
        cst = sigf(gf) * cst + sigf(gi) * tanhff(gg);
        const float h = sigf(go) * tanhff(cst);
        hB[(t + 1) & 1][j >> 3][cc][j & 7] = (_Float16)h;
        h1out[((size_t)(b0 + cc) * kS + (size_t)t) * kH + j] = (_Float16)h;
      }
      __syncthreads();
    }
  }
}

// ---------------- K2: layer-2 via MFMA + head ----------------
// Same structure; K = 256 = [h1(t); h2(t-1)] -> 8 K-tiles, A = 64 VGPR.
__global__ __launch_bounds__(1024) void lstm_l2(
    const _Float16* __restrict__ h1in,
    const float* __restrict__ Wx2, const float* __restrict__ bx2,
    const float* __restrict__ Wh2, const float* __restrict__ bh2,
    const float* __restrict__ Wc,  const float* __restrict__ bc,
    float* __restrict__ out)
{
  const int tid  = threadIdx.x;
  const int b0   = blockIdx.x * 2;
  const int w    = tid >> 6;
  const int q    = (tid >> 4) & 3;
  const int n    = tid & 15;
  const bool real = (n < 2);

  __shared__ __align__(16) _Float16 h1B[8][16][2][8];  // [t][kchunk][n][k&7] 4 KiB
  __shared__ __align__(16) _Float16 h2B[2][16][2][8];  // 1 KiB
  __shared__ __align__(16) float    zslot[4];
  __shared__ float gbuf[2][512];
  __shared__ float hfin[2][128];

  f16x8 A[2][8];
  {
    const int rb = w * 32 + (tid & 15);
#pragma unroll
    for (int s = 0; s < 2; ++s) {
      const int row = rb + s * 16;
#pragma unroll
      for (int kt = 0; kt < 4; ++kt) {
        A[s][kt]     = afrag(Wx2, row, kt * 32 + q * 8, kH);
        A[s][4 + kt] = afrag(Wh2, row, kt * 32 + q * 8, kH);
      }
    }
  }

  float bI = 0.f, bF = 0.f, bG = 0.f, bO = 0.f, cst = 0.f;
  if (tid < 256) {
    const int j = tid & 127;
    bI = bx2[j]       + bh2[j];
    bF = bx2[j + 128] + bh2[j + 128];
    bG = bx2[j + 256] + bh2[j + 256];
    bO = bx2[j + 384] + bh2[j + 384];
  }
  if (tid < 256)      reinterpret_cast<_Float16*>(h2B)[tid] = (_Float16)0.f;
  else if (tid < 260) zslot[tid - 256] = 0.f;

  const int   off = q * 32 + n * 16;
  const char* zp  = reinterpret_cast<const char*>(zslot);

  for (int t0 = 0; t0 < kS; t0 += 8) {
    {  // stage h1 tile (2048 fp16, 2 per thread)
#pragma unroll
      for (int e = tid; e < 2048; e += 1024) {
        const int st = e >> 8, sn = (e >> 7) & 1, sk = e & 127;
        h1B[st][sk >> 3][sn][sk & 7] =
            h1in[((size_t)(b0 + sn) * kS + (size_t)(t0 + st)) * kH + sk];
      }
    }
    __syncthreads();

    for (int dt = 0; dt < 8; ++dt) {
      const int t = t0 + dt;
      const char* xb = reinterpret_cast<const char*>(&h1B[dt][0][0][0]);
      const char* hb = reinterpret_cast<const char*>(&h2B[t & 1][0][0][0]);

      f32x4 d0 = {0.f, 0.f, 0.f, 0.f}, d1 = {0.f, 0.f, 0.f, 0.f};
      {
        const f16x8 bf0 = *reinterpret_cast<const f16x8*>(real ? xb + off       : zp);
        const f16x8 bf1 = *reinterpret_cast<const f16x8*>(real ? xb + 128 + off : zp);
        const f16x8 bf2 = *reinterpret_cast<const f16x8*>(real ? xb + 256 + off : zp);
        const f16x8 bf3 = *reinterpret_cast<const f16x8*>(real ? xb + 384 + off : zp);
        d0 = MFMA16(A[0][0], bf0, d0);  d1 = MFMA16(A[1][0], bf0, d1);
        d0 = MFMA16(A[0][1], bf1, d0);  d1 = MFMA16(A[1][1], bf1, d1);
        d0 = MFMA16(A[0][2], bf2, d0);  d1 = MFMA16(A[1][2], bf2, d1);
        d0 = MFMA16(A[0][3], bf3, d0);  d1 = MFMA16(A[1][3], bf3, d1);
      }
#if __has_builtin(__builtin_amdgcn_sched_barrier)
      __builtin_amdgcn_sched_barrier(0);   // cap B-frag live range (VGPR budget)
#endif
      {
        const f16x8 bf4 = *reinterpret_cast<const f16x8*>(real ? hb + off       : zp);
        const f16x8 bf5 = *reinterpret_cast<const f16x8*>(real ? hb + 128 + off : zp);
        const f16x8 bf6 = *reinterpret_cast<const f16x8*>(real ? hb + 256 + off : zp);
        const f16x8 bf7 = *reinterpret_cast<const f16x8*>(real ? hb + 384 + off : zp);
        d0 = MFMA16(A[0][4], bf4, d0);  d1 = MFMA16(A[1][4], bf4, d1);
        d0 = MFMA16(A[0][5], bf5, d0);  d1 = MFMA16(A[1][5], bf5, d1);
        d0 = MFMA16(A[0][6], bf6, d0);  d1 = MFMA16(A[1][6], bf6, d1);
        d0 = MFMA16(A[0][7], bf7, d0);  d1 = MFMA16(A[1][7], bf7, d1);
      }

      if (real) {
        *reinterpret_cast<f32x4*>(&gbuf[n][w * 32 + q * 4])      = d0;
        *reinterpret_cast<f32x4*>(&gbuf[n][w * 32 + 16 + q * 4]) = d1;
      }
      __syncthreads();

      if (tid < 256) {
        const int cc = tid >> 7, j = tid & 127;
        const float gi = gbuf[cc][j]       + bI;
        const float gf = gbuf[cc][j + 128] + bF;
        const float gg = gbuf[cc][j + 256] + bG;
        const float go = gbuf[cc][j + 384] + bO;
        cst = sigf(gf) * cst + sigf(gi) * tanhff(gg);
        const float h = sigf(go) * tanhff(cst);
        h2B[(t + 1) & 1][j >> 3][cc][j & 7] = (_Float16)h;
        if (t == kS - 1) hfin[cc][j] = h;
      }
      __syncthreads();
    }
  }

  // classifier head: logits[b0+c, m] = Wc[m,:] . h2fin[c] + bc[m]
  if (tid < 8) {
    const int m = tid & 3, c = tid >> 2;
    const float* wr = Wc + (size_t)m * kH;
    float s0 = 0.f, s1 = 0.f, s2 = 0.f, s3 = 0.f;
#pragma unroll
    for (int j = 0; j < kH; j += 4) {
      s0 = fmaf(wr[j],     hfin[c][j],     s0);
      s1 = fmaf(wr[j + 1], hfin[c][j + 1], s1);
      s2 = fmaf(wr[j + 2], hfin[c][j + 2], s2);
      s3 = fmaf(wr[j + 3], hfin[c][j + 3], s3);
    }
    out[(size_t)(b0 + c) * 4 + m] = bc[m] + ((s0 + s1) + (s2 + s3));
  }
}

} // namespace

extern "C" void kernel_launch(void* const* d_in, const int* in_sizes, int n_in,
                              void* d_out, int out_size, void* d_ws, size_t ws_size,
                              hipStream_t stream) {
  const float* x   = (const float*)d_in[0];
  const float* Wx1 = (const float*)d_in[1];
  const float* bx1 = (const float*)d_in[2];
  const float* Wh1 = (const float*)d_in[3];
  const float* bh1 = (const float*)d_in[4];
  const float* Wx2 = (const float*)d_in[5];
  const float* bx2 = (const float*)d_in[6];
  const float* Wh2 = (const float*)d_in[7];
  const float* bh2 = (const float*)d_in[8];
  const float* Wc  = (const float*)d_in[9];
  const float* bc  = (const float*)d_in[10];

  _Float16* h1 = (_Float16*)d_ws;   // 512*1024*128 fp16 = 128 MiB layer-1 stream

  hipLaunchKernelGGL(lstm_l1, dim3(256), dim3(1024), 0, stream,
                     x, Wx1, bx1, Wh1, bh1, h1);
  hipLaunchKernelGGL(lstm_l2, dim3(256), dim3(1024), 0, stream,
                     h1, Wx2, bx2, Wh2, bh2, Wc, bc, (float*)d_out);
}